// Round 2
// baseline (328.942 us; speedup 1.0000x reference)
//
#include <hip/hip_runtime.h>
#include <stdint.h>

#define NEXP 8
#define DD   512
#define BM   64
#define BN   512

typedef short s16x8 __attribute__((ext_vector_type(8)));
typedef float f32x4 __attribute__((ext_vector_type(4)));

static __device__ __forceinline__ unsigned short f2bf(float f) {
    union { float f; unsigned u; } v; v.f = f;
    unsigned r = v.u + 0x7FFFu + ((v.u >> 16) & 1u);   // round-to-nearest-even
    return (unsigned short)(r >> 16);
}

// ---------------- bucketing kernels ----------------

__global__ void hist_kernel(const int* __restrict__ z, int* __restrict__ counts, int T) {
    __shared__ int lc[NEXP];
    int tid = threadIdx.x;
    if (tid < NEXP) lc[tid] = 0;
    __syncthreads();
    int t = blockIdx.x * blockDim.x + tid;
    if (t < T) atomicAdd(&lc[z[t]], 1);
    __syncthreads();
    if (tid < NEXP) atomicAdd(&counts[tid], lc[tid]);
}

__global__ void scan_kernel(const int* __restrict__ counts, int* __restrict__ cursors,
                            int4* __restrict__ table, int max_tiles) {
    __shared__ int off[NEXP + 1];
    __shared__ int tb[NEXP + 1];
    int tid = threadIdx.x;
    if (tid == 0) {
        int o = 0, tbs = 0;
        for (int e = 0; e < NEXP; e++) {
            off[e] = o; tb[e] = tbs;
            cursors[e] = o;
            int c = counts[e];
            o += c;
            tbs += (c + BM - 1) / BM;
        }
        off[NEXP] = o; tb[NEXP] = tbs;
    }
    __syncthreads();
    for (int idx = tid; idx < max_tiles; idx += blockDim.x) {
        int4 ent; ent.x = -1; ent.y = 0; ent.z = 0; ent.w = 0;
#pragma unroll
        for (int e = 0; e < NEXP; e++) {
            if (idx >= tb[e] && idx < tb[e + 1]) {
                int r = (idx - tb[e]) * BM;
                ent.x = e; ent.y = off[e] + r; ent.z = (off[e + 1] - off[e]) - r;
            }
        }
        table[idx] = ent;
    }
}

__global__ void scatter_kernel(const int* __restrict__ z, int* __restrict__ cursors,
                               int* __restrict__ token_index, float* __restrict__ zout, int T) {
    __shared__ int lc[NEXP];
    __shared__ int lbase[NEXP];
    int tid = threadIdx.x;
    if (tid < NEXP) lc[tid] = 0;
    __syncthreads();
    int t = blockIdx.x * blockDim.x + tid;
    int e = 0, rank = 0;
    if (t < T) {
        e = z[t];
        rank = atomicAdd(&lc[e], 1);
        zout[t] = (float)e;            // output 0: z as float
    }
    __syncthreads();
    if (tid < NEXP) lbase[tid] = atomicAdd(&cursors[tid], lc[tid]);
    __syncthreads();
    if (t < T) token_index[lbase[e] + rank] = t;
}

// W [8][k=512][n=512] f32  ->  Wt [8][n=512][k=512] bf16 (transposed, contiguous-k rows)
__global__ void convw_kernel(const float* __restrict__ W, unsigned short* __restrict__ Wt) {
    __shared__ float tile[32][33];
    int e = blockIdx.z, k0 = blockIdx.x * 32, n0 = blockIdx.y * 32;
    int tid = threadIdx.x;
    const float* We = W + (size_t)e * DD * DD;
    unsigned short* WtE = Wt + (size_t)e * DD * DD;
    int c = tid & 31, r0 = tid >> 5;
#pragma unroll
    for (int i = 0; i < 4; i++) {
        int kr = r0 + 8 * i;
        tile[kr][c] = We[(size_t)(k0 + kr) * DD + n0 + c];
    }
    __syncthreads();
#pragma unroll
    for (int i = 0; i < 4; i++) {
        int nr = r0 + 8 * i;
        WtE[(size_t)(n0 + nr) * DD + k0 + c] = f2bf(tile[c][nr]);
    }
}

// ---------------- fused grouped GEMM, barrier-free K-loop ----------------
// BM=64 x BN=512 per block (x read from HBM exactly once).
// Prologue: entire A tile (64x512 f32 -> bf16) staged to 64 KB swizzled LDS,
//           ONE __syncthreads() for the whole block.
// K-loop:   A fragments via ds_read_b128 (XOR-swizzled, conflict-free);
//           B fragments loaded DIRECTLY from Wt (L2-resident, 4 MB) into regs.
//           No LDS writes, no barriers, no vmcnt(0) drains -> compiler
//           software-pipelines loads across iterations; 16 waves/CU interleave.

__global__ __launch_bounds__(512, 4) void gemm4_kernel(
    const float* __restrict__ x,
    const unsigned short* __restrict__ Wt,      // [8][n][k] bf16
    const float* __restrict__ bias,             // [8][512] f32
    const int* __restrict__ token_index,
    const int4* __restrict__ table,
    float* __restrict__ y)                      // [T][512] f32
{
    int4 te = table[blockIdx.x];
    const int e = te.x;
    if (e < 0) return;
    const int base = te.y;
    const int rows_valid = te.z < BM ? te.z : BM;

    __shared__ unsigned short Als[BM * DD];     // 64 KB: [8 kstep][64 row][64 k]

    const int tid  = threadIdx.x;
    const int lane = tid & 63;
    const int wave = tid >> 6;                  // 0..7
    const int wn   = wave * 64;                 // per-wave N offset

    // A staging geometry: thread handles row ra, LDS chunk-slot ca.
    // global chunk = ca ^ (ra&7) (XOR swizzle via the global address).
    const int ra  = tid >> 3;                   // 0..63
    const int ca  = tid & 7;
    const int gca = ca ^ (ra & 7);

    const int rr  = (ra < rows_valid) ? ra : 0;
    const int tok = token_index[base + rr];
    const float* asrc = x + (size_t)tok * DD + gca * 8;

    // prologue: load all of A, convert to bf16, write swizzled LDS
#pragma unroll
    for (int s = 0; s < 8; s++) {
        float4 v0 = *(const float4*)(asrc + s * 64);
        float4 v1 = *(const float4*)(asrc + s * 64 + 4);
        uint4 p;
        p.x = (unsigned)f2bf(v0.x) | ((unsigned)f2bf(v0.y) << 16);
        p.y = (unsigned)f2bf(v0.z) | ((unsigned)f2bf(v0.w) << 16);
        p.z = (unsigned)f2bf(v1.x) | ((unsigned)f2bf(v1.y) << 16);
        p.w = (unsigned)f2bf(v1.z) | ((unsigned)f2bf(v1.w) << 16);
        *(uint4*)(&Als[s * 4096 + tid * 8]) = p;
    }
    __syncthreads();                            // the ONLY barrier

    f32x4 acc[4][4];
#pragma unroll
    for (int i = 0; i < 4; i++)
#pragma unroll
        for (int j = 0; j < 4; j++) acc[i][j] = (f32x4){0.f, 0.f, 0.f, 0.f};

    const int quad = lane >> 4;
    const int lrow = lane & 15;

    // B: per-lane global base (row wn+lrow, byte chunk quad); L2-hit loads
    const unsigned short* bbase = Wt + (size_t)e * DD * DD + (size_t)(wn + lrow) * DD + quad * 8;

#pragma unroll 2
    for (int k0 = 0; k0 < DD; k0 += 64) {
        const int sblk = (k0 >> 6) * 4096;
#pragma unroll
        for (int ks = 0; ks < 2; ks++) {
            s16x8 af[4], bq[4];
#pragma unroll
            for (int i = 0; i < 4; i++) {
                int r = i * 16 + lrow;
                af[i] = *(const s16x8*)(&Als[sblk + r * 64 + (((quad + 4 * ks) ^ (r & 7)) * 8)]);
            }
#pragma unroll
            for (int j = 0; j < 4; j++)
                bq[j] = *(const s16x8*)(bbase + (size_t)j * 16 * DD + k0 + ks * 32);
#pragma unroll
            for (int i = 0; i < 4; i++)
#pragma unroll
                for (int j = 0; j < 4; j++)
                    acc[i][j] = __builtin_amdgcn_mfma_f32_16x16x32_bf16(af[i], bq[j], acc[i][j], 0, 0, 0);
        }
    }

    // epilogue: C/D layout col=lane&15, row=quad*4+reg
    const int lcol = lane & 15;
    float bv[4];
#pragma unroll
    for (int j = 0; j < 4; j++) bv[j] = bias[e * DD + wn + j * 16 + lcol];
#pragma unroll
    for (int i = 0; i < 4; i++) {
#pragma unroll
        for (int reg = 0; reg < 4; reg++) {
            int r = i * 16 + quad * 4 + reg;
            if (r < rows_valid) {
                int t = token_index[base + r];
                float* yr = y + (size_t)t * DD + wn + lcol;
#pragma unroll
                for (int j = 0; j < 4; j++)
                    yr[j * 16] = acc[i][j][reg] + bv[j];
            }
        }
    }
}

// ---------------- host ----------------

extern "C" void kernel_launch(void* const* d_in, const int* in_sizes, int n_in,
                              void* d_out, int out_size, void* d_ws, size_t ws_size,
                              hipStream_t stream) {
    const int*   z = (const int*)d_in[0];
    const float* x = (const float*)d_in[1];
    const float* W = (const float*)d_in[2];
    const float* b = (const float*)d_in[3];
    const int T = in_sizes[0];                 // 65536

    float* zout = (float*)d_out;               // [T] float(z)
    float* y    = (float*)d_out + T;           // [T][512]

    char* ws = (char*)d_ws;
    int*  counts      = (int*)ws;                        // 8 ints @ 0
    int*  cursors     = (int*)(ws + 64);                 // 8 ints
    int4* table       = (int4*)(ws + 256);               // <=1040 entries (16640 B)
    int*  token_index = (int*)(ws + 17408);              // T ints (ends 279552)
    unsigned short* Wt = (unsigned short*)(ws + 279552); // 4 MiB   (ends 4473856)

    const int max_tiles = T / BM + NEXP;       // 1032

    hipMemsetAsync(ws, 0, 64, stream);
    hist_kernel<<<(T + 255) / 256, 256, 0, stream>>>(z, counts, T);
    convw_kernel<<<dim3(DD / 32, DD / 32, NEXP), 256, 0, stream>>>(W, Wt);
    scan_kernel<<<1, 256, 0, stream>>>(counts, cursors, table, max_tiles);
    scatter_kernel<<<(T + 255) / 256, 256, 0, stream>>>(z, cursors, token_index, zout, T);
    gemm4_kernel<<<dim3(max_tiles), 512, 0, stream>>>(x, Wt, b, token_index, table, y);
}

// Round 3
// 327.347 us; speedup vs baseline: 1.0049x; 1.0049x over previous
//
#include <hip/hip_runtime.h>
#include <stdint.h>

#define NEXP 8
#define DD   512
#define BM   128
#define BN   128

typedef short s16x8 __attribute__((ext_vector_type(8)));
typedef float f32x4 __attribute__((ext_vector_type(4)));

static __device__ __forceinline__ unsigned short f2bf(float f) {
    union { float f; unsigned u; } v; v.f = f;
    unsigned r = v.u + 0x7FFFu + ((v.u >> 16) & 1u);   // round-to-nearest-even
    return (unsigned short)(r >> 16);
}

// packed f32x2 -> bf16x2 (RNE), single VOP3 instruction
static __device__ __forceinline__ unsigned cvtpk(float lo, float hi) {
    unsigned r;
    asm("v_cvt_pk_bf16_f32 %0, %1, %2" : "=v"(r) : "v"(lo), "v"(hi));
    return r;
}

// ---------------- K1: fused convw + hist ----------------
// blocks [0,2048): W [8][k][n] f32 -> Wt [8][n][k] bf16 (transposed)
// blocks [2048,2304): histogram of z into counts[8]

__global__ __launch_bounds__(256) void prep1_kernel(const float* __restrict__ W,
                                                    unsigned short* __restrict__ Wt,
                                                    const int* __restrict__ z,
                                                    int* __restrict__ counts, int T) {
    const int bx = blockIdx.x;
    const int tid = threadIdx.x;
    if (bx < 2048) {
        __shared__ float tile[32][33];
        const int e = bx >> 8;
        const int b = bx & 255;
        const int k0 = (b & 15) * 32;
        const int n0 = (b >> 4) * 32;
        const float* We = W + (size_t)e * DD * DD;
        unsigned short* WtE = Wt + (size_t)e * DD * DD;
        const int c = tid & 31, r0 = tid >> 5;
#pragma unroll
        for (int i = 0; i < 4; i++) {
            int kr = r0 + 8 * i;
            tile[kr][c] = We[(size_t)(k0 + kr) * DD + n0 + c];
        }
        __syncthreads();
#pragma unroll
        for (int i = 0; i < 4; i++) {
            int nr = r0 + 8 * i;
            WtE[(size_t)(n0 + nr) * DD + k0 + c] = f2bf(tile[c][nr]);
        }
    } else {
        __shared__ int lc[NEXP];
        if (tid < NEXP) lc[tid] = 0;
        __syncthreads();
        int t = (bx - 2048) * 256 + tid;
        if (t < T) atomicAdd(&lc[z[t]], 1);
        __syncthreads();
        if (tid < NEXP) atomicAdd(&counts[tid], lc[tid]);
    }
}

// ---------------- K2: scatter (scan folded in) ----------------
// Computes per-expert exclusive offsets from counts in-block, grabs a global
// chunk via atomic cursors, writes token_index + zout. Order within an expert
// is arbitrary (legal: scatter-back is via token_index).

__global__ __launch_bounds__(256) void scatter_kernel(const int* __restrict__ z,
                                                      const int* __restrict__ counts,
                                                      int* __restrict__ cursors,
                                                      int* __restrict__ token_index,
                                                      float* __restrict__ zout, int T) {
    __shared__ int lc[NEXP];
    __shared__ int off[NEXP];
    __shared__ int lbase[NEXP];
    const int tid = threadIdx.x;
    if (tid < NEXP) lc[tid] = 0;
    if (tid == 0) {
        int o = 0;
#pragma unroll
        for (int e = 0; e < NEXP; e++) { off[e] = o; o += counts[e]; }
    }
    __syncthreads();
    int t = blockIdx.x * blockDim.x + tid;
    int e = 0, rank = 0;
    if (t < T) {
        e = z[t];
        rank = atomicAdd(&lc[e], 1);
        zout[t] = (float)e;            // output 0: z as float
    }
    __syncthreads();
    if (tid < NEXP) lbase[tid] = off[tid] + atomicAdd(&cursors[tid], lc[tid]);
    __syncthreads();
    if (t < T) token_index[lbase[e] + rank] = t;
}

// ---------------- K3: fused grouped GEMM (round-0 gemm2 structure) ----------------
// BM=128 x BN=128, BK=64, 256 threads, 32 KB LDS, ~16 waves/CU.
// B: global_load_lds from Wt with pre-swizzled global source (chunk ^ (row&7)),
//    LDS linear dest -> conflict-free ds_read_b128 fragments.
// A: staged directly from f32 x (no gather pass): 8x dwordx4 loads ->
//    v_cvt_pk_bf16_f32 pack -> 4 swizzled ds_write_b128 per thread per k-step.
//    LDS layout bit-identical to the gll path.
// Block self-computes (expert, base, rows) from counts[8] (no scan/table).

__global__ __launch_bounds__(256) void gemm5_kernel(
    const float* __restrict__ x,
    const unsigned short* __restrict__ Wt,      // [8][n][k] bf16
    const float* __restrict__ bias,             // [8][512] f32
    const int* __restrict__ token_index,
    const int* __restrict__ counts,
    float* __restrict__ y)                      // [T][512] f32
{
    __shared__ unsigned short Als[BM * 64];     // 16 KB
    __shared__ unsigned short Bls[BN * 64];     // 16 KB
    __shared__ int meta[3];

    const int tid = threadIdx.x;
    if (tid == 0) {
        int o = 0, tb = 0, e = -1, base = 0, rows = 0;
#pragma unroll
        for (int ee = 0; ee < NEXP; ee++) {
            int c = counts[ee];
            int nt = (c + BM - 1) >> 7;
            int ib = (int)blockIdx.x - tb;
            if (ib >= 0 && ib < nt) { e = ee; base = o + (ib << 7); rows = c - (ib << 7); }
            o += c; tb += nt;
        }
        meta[0] = e; meta[1] = base; meta[2] = rows < BM ? rows : BM;
    }
    __syncthreads();
    const int e = meta[0];
    if (e < 0) return;
    const int base = meta[1];
    const int rows_valid = meta[2];
    const int n0 = blockIdx.y * BN;

    const int lane = tid & 63;
    const int wave = tid >> 6;
    const int wm = (wave & 1) * 64;
    const int wn = (wave >> 1) * 64;

    // staging slots: slot s = wave*256 + q*64 + lane; row = s>>3, chunk-slot = s&7;
    // global chunk = cs ^ (row&7)  (XOR swizzle applied on the GLOBAL side)
    int srow[4], sgc[4];
    const float* aptr[4];
#pragma unroll
    for (int q = 0; q < 4; q++) {
        int s = wave * 256 + q * 64 + lane;
        srow[q] = s >> 3;
        sgc[q]  = (s & 7) ^ ((s >> 3) & 7);
        int rr = srow[q] < rows_valid ? srow[q] : rows_valid - 1;
        aptr[q] = x + (size_t)token_index[base + rr] * DD + sgc[q] * 8;
    }
    const unsigned short* WtE = Wt + (size_t)e * DD * DD;

    f32x4 acc[4][4];
#pragma unroll
    for (int i = 0; i < 4; i++)
#pragma unroll
        for (int j = 0; j < 4; j++) acc[i][j] = (f32x4){0.f, 0.f, 0.f, 0.f};

    const int quad = lane >> 4;
    const int lrow = lane & 15;

    for (int k0 = 0; k0 < DD; k0 += 64) {
        __syncthreads();
        // B: 4 direct-to-LDS 16B loads (pre-swizzled source, linear dest)
#pragma unroll
        for (int q = 0; q < 4; q++) {
            const unsigned short* gb = WtE + (size_t)(n0 + srow[q]) * DD + k0 + sgc[q] * 8;
            unsigned short* lb = &Bls[(size_t)(wave * 256 + q * 64) * 8];
            __builtin_amdgcn_global_load_lds((const __attribute__((address_space(1))) void*)gb,
                                             (__attribute__((address_space(3))) void*)lb, 16, 0, 0);
        }
        // A: 8 f32x4 loads (issued together), pack to bf16, swizzled ds_write
        float4 va[4][2];
#pragma unroll
        for (int q = 0; q < 4; q++) {
            va[q][0] = *(const float4*)(aptr[q] + k0);
            va[q][1] = *(const float4*)(aptr[q] + k0 + 4);
        }
#pragma unroll
        for (int q = 0; q < 4; q++) {
            uint4 p;
            p.x = cvtpk(va[q][0].x, va[q][0].y);
            p.y = cvtpk(va[q][0].z, va[q][0].w);
            p.z = cvtpk(va[q][1].x, va[q][1].y);
            p.w = cvtpk(va[q][1].z, va[q][1].w);
            *(uint4*)(&Als[(size_t)(wave * 256 + q * 64 + lane) * 8]) = p;
        }
        __syncthreads();

#pragma unroll
        for (int ks = 0; ks < 2; ks++) {
            s16x8 af[4], bq[4];
#pragma unroll
            for (int i = 0; i < 4; i++) {
                int r = wm + i * 16 + lrow;
                af[i] = *(const s16x8*)(&Als[r * 64 + (((quad + 4 * ks) ^ (r & 7)) * 8)]);
            }
#pragma unroll
            for (int j = 0; j < 4; j++) {
                int r = wn + j * 16 + lrow;
                bq[j] = *(const s16x8*)(&Bls[r * 64 + (((quad + 4 * ks) ^ (r & 7)) * 8)]);
            }
#pragma unroll
            for (int i = 0; i < 4; i++)
#pragma unroll
                for (int j = 0; j < 4; j++)
                    acc[i][j] = __builtin_amdgcn_mfma_f32_16x16x32_bf16(af[i], bq[j], acc[i][j], 0, 0, 0);
        }
    }

    // epilogue: C/D layout col=lane&15, row=quad*4+reg; nontemporal y stores
    const int lcol = lane & 15;
    float bv[4];
#pragma unroll
    for (int j = 0; j < 4; j++) bv[j] = bias[e * DD + n0 + wn + j * 16 + lcol];
#pragma unroll
    for (int i = 0; i < 4; i++) {
#pragma unroll
        for (int reg = 0; reg < 4; reg++) {
            int r = wm + i * 16 + quad * 4 + reg;
            if (r < rows_valid) {
                int t = token_index[base + r];
                float* yr = y + (size_t)t * DD + n0 + wn + lcol;
#pragma unroll
                for (int j = 0; j < 4; j++)
                    __builtin_nontemporal_store(acc[i][j][reg] + bv[j], yr + j * 16);
            }
        }
    }
}

// ---------------- host ----------------

extern "C" void kernel_launch(void* const* d_in, const int* in_sizes, int n_in,
                              void* d_out, int out_size, void* d_ws, size_t ws_size,
                              hipStream_t stream) {
    const int*   z = (const int*)d_in[0];
    const float* x = (const float*)d_in[1];
    const float* W = (const float*)d_in[2];
    const float* b = (const float*)d_in[3];
    const int T = in_sizes[0];                 // 65536

    float* zout = (float*)d_out;               // [T] float(z)
    float* y    = (float*)d_out + T;           // [T][512]

    char* ws = (char*)d_ws;
    int*  counts      = (int*)ws;                        // 8 ints @ 0
    int*  cursors     = (int*)(ws + 64);                 // 8 ints
    int*  token_index = (int*)(ws + 17408);              // T ints (ends 279552)
    unsigned short* Wt = (unsigned short*)(ws + 279552); // 4 MiB   (ends 4473856)

    const int max_tiles = T / BM + NEXP;       // 520
    const int hist_blocks = (T + 255) / 256;   // 256

    hipMemsetAsync(ws, 0, 128, stream);        // counts + cursors
    prep1_kernel<<<2048 + hist_blocks, 256, 0, stream>>>(W, Wt, z, counts, T);
    scatter_kernel<<<hist_blocks, 256, 0, stream>>>(z, counts, cursors, token_index, zout, T);
    gemm5_kernel<<<dim3(max_tiles, DD / BN), 256, 0, stream>>>(x, Wt, b, token_index, counts, y);
}

// Round 6
// 318.335 us; speedup vs baseline: 1.0333x; 1.0283x over previous
//
#include <hip/hip_runtime.h>
#include <stdint.h>

#define NEXP 8
#define DD   512
#define BM   128
#define BN   128

typedef short s16x8 __attribute__((ext_vector_type(8)));
typedef float f32x4 __attribute__((ext_vector_type(4)));

static __device__ __forceinline__ unsigned short f2bf(float f) {
    union { float f; unsigned u; } v; v.f = f;
    unsigned r = v.u + 0x7FFFu + ((v.u >> 16) & 1u);   // round-to-nearest-even
    return (unsigned short)(r >> 16);
}

// packed f32x2 -> bf16x2 (RNE), single VOP3 instruction
static __device__ __forceinline__ unsigned cvtpk(float lo, float hi) {
    unsigned r;
    asm("v_cvt_pk_bf16_f32 %0, %1, %2" : "=v"(r) : "v"(lo), "v"(hi));
    return r;
}

// ---------------- K1: fused convw + hist ----------------
// blocks [0,2048): W [8][k][n] f32 -> Wt [8][n][k] bf16 (transposed)
// blocks [2048,2304): histogram of z into counts[8]

__global__ __launch_bounds__(256) void prep1_kernel(const float* __restrict__ W,
                                                    unsigned short* __restrict__ Wt,
                                                    const int* __restrict__ z,
                                                    int* __restrict__ counts, int T) {
    const int bx = blockIdx.x;
    const int tid = threadIdx.x;
    if (bx < 2048) {
        __shared__ float tile[32][33];
        const int e = bx >> 8;
        const int b = bx & 255;
        const int k0 = (b & 15) * 32;
        const int n0 = (b >> 4) * 32;
        const float* We = W + (size_t)e * DD * DD;
        unsigned short* WtE = Wt + (size_t)e * DD * DD;
        const int c = tid & 31, r0 = tid >> 5;
#pragma unroll
        for (int i = 0; i < 4; i++) {
            int kr = r0 + 8 * i;
            tile[kr][c] = We[(size_t)(k0 + kr) * DD + n0 + c];
        }
        __syncthreads();
#pragma unroll
        for (int i = 0; i < 4; i++) {
            int nr = r0 + 8 * i;
            WtE[(size_t)(n0 + nr) * DD + k0 + c] = f2bf(tile[c][nr]);
        }
    } else {
        __shared__ int lc[NEXP];
        if (tid < NEXP) lc[tid] = 0;
        __syncthreads();
        int t = (bx - 2048) * 256 + tid;
        if (t < T) atomicAdd(&lc[z[t]], 1);
        __syncthreads();
        if (tid < NEXP) atomicAdd(&counts[tid], lc[tid]);
    }
}

// ---------------- K2: scatter (scan folded in) ----------------

__global__ __launch_bounds__(256) void scatter_kernel(const int* __restrict__ z,
                                                      const int* __restrict__ counts,
                                                      int* __restrict__ cursors,
                                                      int* __restrict__ token_index,
                                                      float* __restrict__ zout, int T) {
    __shared__ int lc[NEXP];
    __shared__ int off[NEXP];
    __shared__ int lbase[NEXP];
    const int tid = threadIdx.x;
    if (tid < NEXP) lc[tid] = 0;
    if (tid == 0) {
        int o = 0;
#pragma unroll
        for (int e = 0; e < NEXP; e++) { off[e] = o; o += counts[e]; }
    }
    __syncthreads();
    int t = blockIdx.x * blockDim.x + tid;
    int e = 0, rank = 0;
    if (t < T) {
        e = z[t];
        rank = atomicAdd(&lc[e], 1);
        zout[t] = (float)e;            // output 0: z as float
    }
    __syncthreads();
    if (tid < NEXP) lbase[tid] = off[tid] + atomicAdd(&cursors[tid], lc[tid]);
    __syncthreads();
    if (t < T) token_index[lbase[e] + rank] = t;
}

// ---------------- K3: fused grouped GEMM with XCD-sibling grid ----------------
// Identical tile/staging/fragment structure to gemm5 (proven: 0 bank conflicts).
// Grid is 1D; hw block id b decodes to (tile t, nblock j) such that the 4
// N-blocks of a tile get ids {32g+x, +8, +16, +24} (x = t&7): same XCD under
// round-robin dispatch AND temporally adjacent -> x-rows are fetched from HBM
// once per tile, 3/4 of A-staging reads hit that XCD's L2. Wt (4 MB) is fully
// L2-resident per XCD.

__global__ __launch_bounds__(256) void gemm6_kernel(
    const float* __restrict__ x,
    const unsigned short* __restrict__ Wt,      // [8][n][k] bf16
    const float* __restrict__ bias,             // [8][512] f32
    const int* __restrict__ token_index,
    const int* __restrict__ counts,
    float* __restrict__ y)                      // [T][512] f32
{
    __shared__ unsigned short Als[BM * 64];     // 16 KB
    __shared__ unsigned short Bls[BN * 64];     // 16 KB
    __shared__ int meta[3];

    // decode hw id -> (tile, nblock), XCD-sibling grouping
    const int b   = blockIdx.x;
    const int g   = b >> 5;
    const int r   = b & 31;
    const int jnb = r >> 3;                     // 0..3
    const int til = (g << 3) | (r & 7);         // 0..519
    const int n0  = jnb * BN;

    const int tid = threadIdx.x;
    if (tid == 0) {
        int o = 0, tb = 0, e = -1, base = 0, rows = 0;
#pragma unroll
        for (int ee = 0; ee < NEXP; ee++) {
            int c = counts[ee];
            int nt = (c + BM - 1) >> 7;
            int ib = til - tb;
            if (ib >= 0 && ib < nt) { e = ee; base = o + (ib << 7); rows = c - (ib << 7); }
            o += c; tb += nt;
        }
        meta[0] = e; meta[1] = base; meta[2] = rows < BM ? rows : BM;
    }
    __syncthreads();
    const int e = meta[0];
    if (e < 0) return;
    const int base = meta[1];
    const int rows_valid = meta[2];

    const int lane = tid & 63;
    const int wave = tid >> 6;
    const int wm = (wave & 1) * 64;
    const int wn = (wave >> 1) * 64;

    // staging slots: slot s = wave*256 + q*64 + lane; row = s>>3, chunk-slot = s&7;
    // global chunk = cs ^ (row&7)  (XOR swizzle applied on the GLOBAL side)
    int srow[4], sgc[4];
    const float* aptr[4];
#pragma unroll
    for (int q = 0; q < 4; q++) {
        int s = wave * 256 + q * 64 + lane;
        srow[q] = s >> 3;
        sgc[q]  = (s & 7) ^ ((s >> 3) & 7);
        int rr = srow[q] < rows_valid ? srow[q] : rows_valid - 1;
        aptr[q] = x + (size_t)token_index[base + rr] * DD + sgc[q] * 8;
    }
    const unsigned short* WtE = Wt + (size_t)e * DD * DD;

    f32x4 acc[4][4];
#pragma unroll
    for (int i = 0; i < 4; i++)
#pragma unroll
        for (int j = 0; j < 4; j++) acc[i][j] = (f32x4){0.f, 0.f, 0.f, 0.f};

    const int quad = lane >> 4;
    const int lrow = lane & 15;

    for (int k0 = 0; k0 < DD; k0 += 64) {
        __syncthreads();
        // A loads first (longest latency starts earliest) ...
        float4 va[4][2];
#pragma unroll
        for (int q = 0; q < 4; q++) {
            va[q][0] = *(const float4*)(aptr[q] + k0);
            va[q][1] = *(const float4*)(aptr[q] + k0 + 4);
        }
        // ... then B direct-to-LDS (pre-swizzled source, linear dest)
#pragma unroll
        for (int q = 0; q < 4; q++) {
            const unsigned short* gb = WtE + (size_t)(n0 + srow[q]) * DD + k0 + sgc[q] * 8;
            unsigned short* lb = &Bls[(size_t)(wave * 256 + q * 64) * 8];
            __builtin_amdgcn_global_load_lds((const __attribute__((address_space(1))) void*)gb,
                                             (__attribute__((address_space(3))) void*)lb, 16, 0, 0);
        }
        // pack A to bf16, swizzled ds_write
#pragma unroll
        for (int q = 0; q < 4; q++) {
            uint4 p;
            p.x = cvtpk(va[q][0].x, va[q][0].y);
            p.y = cvtpk(va[q][0].z, va[q][0].w);
            p.z = cvtpk(va[q][1].x, va[q][1].y);
            p.w = cvtpk(va[q][1].z, va[q][1].w);
            *(uint4*)(&Als[(size_t)(wave * 256 + q * 64 + lane) * 8]) = p;
        }
        __syncthreads();

#pragma unroll
        for (int ks = 0; ks < 2; ks++) {
            s16x8 af[4], bq[4];
#pragma unroll
            for (int i = 0; i < 4; i++) {
                int rr2 = wm + i * 16 + lrow;
                af[i] = *(const s16x8*)(&Als[rr2 * 64 + (((quad + 4 * ks) ^ (rr2 & 7)) * 8)]);
            }
#pragma unroll
            for (int j = 0; j < 4; j++) {
                int rr2 = wn + j * 16 + lrow;
                bq[j] = *(const s16x8*)(&Bls[rr2 * 64 + (((quad + 4 * ks) ^ (rr2 & 7)) * 8)]);
            }
#pragma unroll
            for (int i = 0; i < 4; i++)
#pragma unroll
                for (int j = 0; j < 4; j++)
                    acc[i][j] = __builtin_amdgcn_mfma_f32_16x16x32_bf16(af[i], bq[j], acc[i][j], 0, 0, 0);
        }
    }

    // epilogue: C/D layout col=lane&15, row=quad*4+reg; nontemporal y stores
    const int lcol = lane & 15;
    float bv[4];
#pragma unroll
    for (int j = 0; j < 4; j++) bv[j] = bias[e * DD + n0 + wn + j * 16 + lcol];
#pragma unroll
    for (int i = 0; i < 4; i++) {
#pragma unroll
        for (int reg = 0; reg < 4; reg++) {
            int rr2 = wm + i * 16 + quad * 4 + reg;
            if (rr2 < rows_valid) {
                int t = token_index[base + rr2];
                float* yr = y + (size_t)t * DD + n0 + wn + lcol;
#pragma unroll
                for (int j = 0; j < 4; j++)
                    __builtin_nontemporal_store(acc[i][j][reg] + bv[j], yr + j * 16);
            }
        }
    }
}

// ---------------- host ----------------

extern "C" void kernel_launch(void* const* d_in, const int* in_sizes, int n_in,
                              void* d_out, int out_size, void* d_ws, size_t ws_size,
                              hipStream_t stream) {
    const int*   z = (const int*)d_in[0];
    const float* x = (const float*)d_in[1];
    const float* W = (const float*)d_in[2];
    const float* b = (const float*)d_in[3];
    const int T = in_sizes[0];                 // 65536

    float* zout = (float*)d_out;               // [T] float(z)
    float* y    = (float*)d_out + T;           // [T][512]

    char* ws = (char*)d_ws;
    int*  counts      = (int*)ws;                        // 8 ints @ 0
    int*  cursors     = (int*)(ws + 64);                 // 8 ints
    int*  token_index = (int*)(ws + 17408);              // T ints (ends 279552)
    unsigned short* Wt = (unsigned short*)(ws + 279552); // 4 MiB   (ends 4473856)

    const int max_tiles = T / BM + NEXP;       // 520
    const int hist_blocks = (T + 255) / 256;   // 256

    hipMemsetAsync(ws, 0, 128, stream);        // counts + cursors
    prep1_kernel<<<2048 + hist_blocks, 256, 0, stream>>>(W, Wt, z, counts, T);
    scatter_kernel<<<hist_blocks, 256, 0, stream>>>(z, counts, cursors, token_index, zout, T);
    gemm6_kernel<<<max_tiles * 4, 256, 0, stream>>>(x, Wt, b, token_index, counts, y);
}